// Round 10
// baseline (205.965 us; speedup 1.0000x reference)
//
#include <hip/hip_runtime.h>
#include <hip/hip_bf16.h>
#include <hip/hip_fp16.h>
#include <math.h>

// B=4, N=1024, C=512, H=8, D=64
// ws layout (bytes):
//   qb   us  @ 0          (4,194,304)
//   kb   us  @ 4194304    (4,194,304)
//   vTb  us  @ 8388608    (4,194,304)
//   apos f32 @ 12582912   (1,048,576)
//   xb   us  @ 13631488   (4,194,304)   [dead after qkv]
// nparts==3 (ws_size >= 31,195,136):
//   wTh @ 17825792, wTl @ 19398656      [dead after qkv]
//   outp1 f32 @ 13631488 (8,388,608)    [overlays xb/wTh/wTl]
//   outp2 f32 @ 22020096 (8,388,608)
//   ml0/1/2   @ 30408704/30670848/30932992 (262,144 each) -> end 31,195,136
// nparts==2 (fallback, 24 MB proven):
//   wTh @ 22020096, wTl @ 23592960
//   outp1 @ 13631488; ml0 @ 22020096, ml1 @ 22282240 (alias wT, dead)
// d_out holds part-0 unnormalized f32; combine rewrites it in place
// (thread i reads floats [4i,4i+4) and writes the same -> no cross-thread race).
//
// R8 resubmit (R9 was a broker timeout): (a) key-split nparts=3 when ws
// allows -> grid 768 = 3 blocks/CU (R7 was grid-limited at 2); (b) qkv 2-pass
// (xb bf16 single; w hi/lo) with 128x64 tiles -> grid 768, LDS 43.5 KB.

typedef __attribute__((ext_vector_type(8))) short bh8;   // 8 bf16 in 4 VGPRs
typedef __attribute__((ext_vector_type(4))) float f32x4;

#define LOG2E 1.44269504f

static __device__ __forceinline__ ushort f2bf(float x) {
    __hip_bfloat16 h = __float2bfloat16(x);
    return *reinterpret_cast<ushort*>(&h);
}
static __device__ __forceinline__ float bf2f(ushort u) {
    unsigned v = ((unsigned)u) << 16;
    return __builtin_bit_cast(float, v);
}
static __device__ __forceinline__ ushort f2h(float x) {
    __half h = __float2half(x);
    return *reinterpret_cast<ushort*>(&h);
}
static __device__ __forceinline__ float h2f(ushort u) {
    __half h = __builtin_bit_cast(__half, u);
    return __half2float(h);
}

// ---------------- kernel 0: fused prep (cast_x | pos_w1 | cast_wT) ----------
// grid: [0,2048) cast_x(bf16 single), [2048,3072) pos_w1, [3072,3264) cast_wT
__global__ __launch_bounds__(256) void prep_kernel(
    const float* __restrict__ x, const float* __restrict__ pos,
    const float* __restrict__ w1, const float* __restrict__ wqkv,
    ushort* __restrict__ xb,
    ushort* __restrict__ wTh, ushort* __restrict__ wTl,
    float* __restrict__ apos)
{
    __shared__ float t[64][65];
    const int bid = blockIdx.x;
    const int tid = threadIdx.x;

    if (bid < 2048) {
        // ---- cast_x: x -> bf16 ----
        const int idx = bid * 256 + tid;              // < 524288
        const float4 v = *(const float4*)&x[(size_t)idx * 4];
        uint2 hu;
        hu.x = (unsigned)f2bf(v.x) | ((unsigned)f2bf(v.y) << 16);
        hu.y = (unsigned)f2bf(v.z) | ((unsigned)f2bf(v.w) << 16);
        *(uint2*)&xb[(size_t)idx * 4] = hu;
    } else if (bid < 3072) {
        // ---- pos_w1: apos = pos @ w1 ----
        const int idx = (bid - 2048) * 256 + tid;     // < 262144
        const int bn = idx >> 6, j = idx & 63;
        const float px = pos[bn * 3 + 0];
        const float py = pos[bn * 3 + 1];
        const float pz = pos[bn * 3 + 2];
        apos[idx] = fmaf(px, w1[j], fmaf(py, w1[64 + j], pz * w1[128 + j]));
    } else {
        // ---- cast_wT: transpose + hi/lo split ----
        const int tb = bid - 3072;                    // 0..191
        const int n0 = (tb % 24) * 64;
        const int k0 = (tb / 24) * 64;
        const int c = tid & 63, r4 = tid >> 6;
#pragma unroll
        for (int i = 0; i < 16; ++i) {
            const int r = i * 4 + r4;                 // k-local
            t[r][c] = wqkv[(size_t)(k0 + r) * 1536 + n0 + c];
        }
        __syncthreads();
#pragma unroll
        for (int i = 0; i < 16; ++i) {
            const int r = i * 4 + r4;                 // n-local
            const float v = t[c][r];
            const ushort hv = f2bf(v);
            wTh[(size_t)(n0 + r) * 512 + k0 + c] = hv;
            wTl[(size_t)(n0 + r) * 512 + k0 + c] = f2bf(v - bf2f(hv));
        }
    }
}

// ---------------- kernel 1: qkv GEMM, 2-pass split MFMA, 128x64 tile --------
// C = xb*(wh + wl) (fp32 acc) + bias; q scaled by 0.125*log2e.
// grid (32, 24); 256 threads = 4 waves; wave w -> rows w*32..+31, all 64 cols.
__global__ __launch_bounds__(256, 3) void qkv_mfma(
    const ushort* __restrict__ xb,
    const ushort* __restrict__ wTh, const ushort* __restrict__ wTl,
    const float* __restrict__ bqkv,
    ushort* __restrict__ qb, ushort* __restrict__ kb, ushort* __restrict__ vTb)
{
    __shared__ ushort Ab[128 * 68], Bh[64 * 68], Bl[64 * 68];   // 43.5 KB
    const int tid = threadIdx.x;
    const int m0 = blockIdx.x * 128;
    const int n0 = blockIdx.y * 64;
    const int wid = tid >> 6, lane = tid & 63;
    const int lq = lane & 15, g = lane >> 4;

    f32x4 acc[2][4];
#pragma unroll
    for (int m = 0; m < 2; ++m)
#pragma unroll
        for (int n = 0; n < 4; ++n) acc[m][n] = (f32x4){0.f, 0.f, 0.f, 0.f};

    const int arow = tid >> 3;          // 0..31
    const int ac = (tid & 7) * 8;       // 0..56
    const int brow = tid >> 2;          // 0..63
    const int bc = (tid & 3) * 16;      // 0,16,32,48

    for (int kt = 0; kt < 8; ++kt) {
        const int kk0 = kt * 64;
        __syncthreads();
#pragma unroll
        for (int i = 0; i < 4; ++i) {
            const int row = i * 32 + arow;
            *(bh8*)&Ab[row * 68 + ac] =
                *(const bh8*)&xb[(size_t)(m0 + row) * 512 + kk0 + ac];
        }
        *(bh8*)&Bh[brow * 68 + bc] =
            *(const bh8*)&wTh[(size_t)(n0 + brow) * 512 + kk0 + bc];
        *(bh8*)&Bh[brow * 68 + bc + 8] =
            *(const bh8*)&wTh[(size_t)(n0 + brow) * 512 + kk0 + bc + 8];
        *(bh8*)&Bl[brow * 68 + bc] =
            *(const bh8*)&wTl[(size_t)(n0 + brow) * 512 + kk0 + bc];
        *(bh8*)&Bl[brow * 68 + bc + 8] =
            *(const bh8*)&wTl[(size_t)(n0 + brow) * 512 + kk0 + bc + 8];
        __syncthreads();
#pragma unroll
        for (int kc = 0; kc < 2; ++kc) {
            const int ko = kc * 32 + g * 8;
            bh8 af[2], bfh[4], bfl[4];
#pragma unroll
            for (int m = 0; m < 2; ++m)
                af[m] = *(const bh8*)&Ab[(wid * 32 + m * 16 + lq) * 68 + ko];
#pragma unroll
            for (int n = 0; n < 4; ++n) {
                bfh[n] = *(const bh8*)&Bh[(n * 16 + lq) * 68 + ko];
                bfl[n] = *(const bh8*)&Bl[(n * 16 + lq) * 68 + ko];
            }
#pragma unroll
            for (int m = 0; m < 2; ++m)
#pragma unroll
                for (int n = 0; n < 4; ++n) {
                    acc[m][n] = __builtin_amdgcn_mfma_f32_16x16x32_bf16(
                        af[m], bfh[n], acc[m][n], 0, 0, 0);
                    acc[m][n] = __builtin_amdgcn_mfma_f32_16x16x32_bf16(
                        af[m], bfl[n], acc[m][n], 0, 0, 0);
                }
        }
    }

    // ---- epilogue: D col=lq (out col), row=g*4+r (x row); h uniform/block ----
    const int s = n0 >> 9;              // 0:q 1:k 2:v
    const int h = (n0 >> 6) & 7;
    const float QSCALE = 0.125f * LOG2E;
#pragma unroll
    for (int ntf = 0; ntf < 4; ++ntf) {
        const int col = n0 + ntf * 16 + lq;
        const float bias_v = bqkv[col];
        const int d = col & 63;
#pragma unroll
        for (int mf = 0; mf < 2; ++mf) {
            const int row = m0 + wid * 32 + mf * 16 + g * 4;
            const int b = row >> 10, nloc = row & 1023;
            const float v0 = acc[mf][ntf][0] + bias_v;
            const float v1 = acc[mf][ntf][1] + bias_v;
            const float v2 = acc[mf][ntf][2] + bias_v;
            const float v3 = acc[mf][ntf][3] + bias_v;
            if (s == 0) {
                const size_t base = ((size_t)(b * 8 + h) * 1024 + nloc) * 64 + d;
                qb[base]       = f2bf(v0 * QSCALE);
                qb[base + 64]  = f2bf(v1 * QSCALE);
                qb[base + 128] = f2bf(v2 * QSCALE);
                qb[base + 192] = f2bf(v3 * QSCALE);
            } else if (s == 1) {
                const size_t base = ((size_t)(b * 8 + h) * 1024 + nloc) * 64 + d;
                kb[base]       = f2bf(v0);
                kb[base + 64]  = f2bf(v1);
                kb[base + 128] = f2bf(v2);
                kb[base + 192] = f2bf(v3);
            } else {
                uint2 u;
                u.x = (unsigned)f2bf(v0) | ((unsigned)f2bf(v1) << 16);
                u.y = (unsigned)f2bf(v2) | ((unsigned)f2bf(v3) << 16);
                *(uint2*)&vTb[((size_t)(b * 8 + h) * 64 + d) * 1024 + nloc] = u;
            }
        }
    }
}

// ---------------- kernel 2: fused bias-MLP + flash attention (key-split) -----
// grid = 256*nparts blocks = (batch, 16-query tile, key part); 8 waves.
__global__ __launch_bounds__(512, 4) void attn_fused(
    const ushort* __restrict__ qb, const ushort* __restrict__ kb,
    const ushort* __restrict__ vTb, const float* __restrict__ apos,
    const float* __restrict__ pos, const float* __restrict__ b1,
    const float* __restrict__ w2, const float* __restrict__ b2,
    float* __restrict__ outp0, float* __restrict__ outp1,
    float* __restrict__ outp2,
    float* __restrict__ ml0, float* __restrict__ ml1,
    float* __restrict__ ml2, int nparts)
{
    const int bx = blockIdx.x;
    const int xcd = bx & 7;             // XCD swizzle: 2 XCDs per batch
    const int b = xcd >> 1;
    const int u = (bx >> 3) * 2 + (xcd & 1);
    const int nq0 = (u & 63) * 16;
    const int part = u >> 6;            // 0..nparts-1
    int k0, nt;
    if (nparts == 2) { k0 = part * 512; nt = 8; }
    else { k0 = (part == 0) ? 0 : (part == 1 ? 384 : 704); nt = (part == 0) ? 6 : 5; }

    float* __restrict__ outp = (part == 0) ? outp0 : (part == 1 ? outp1 : outp2);
    float* __restrict__ mlp  = (part == 0) ? ml0 : (part == 1 ? ml1 : ml2);

    const int tid = threadIdx.x;
    const int w = tid >> 6;             // wave id == head
    const int lane = tid & 63;
    const int lq = lane & 15;
    const int g = lane >> 4;

    // LDS: 16384 + 1024 + 17600 + 18432 + 576 = 54016 B -> 3 blocks/CU
    __shared__ __align__(16) float a_m_s[64][64];      // 16 KB
    __shared__ __align__(16) float pos_k_s[64][4];     // 1 KB
    __shared__ __align__(16) ushort bias_s[8 * 1100];  // 17.2 KB f16
    __shared__ __align__(16) ushort p_lds[8][16][72];  // 18 KB bf16
    __shared__ float red_s[8][18];                     // 0.56 KB

    // ---- per-lane loop-invariant registers ----
    float a_n[16], b1r[16];
    {
        const float* anp = apos + (size_t)(b * 1024 + nq0 + lq) * 64;
        *(float4*)&a_n[0]  = *(const float4*)&anp[g * 8];
        *(float4*)&a_n[4]  = *(const float4*)&anp[g * 8 + 4];
        *(float4*)&a_n[8]  = *(const float4*)&anp[32 + g * 8];
        *(float4*)&a_n[12] = *(const float4*)&anp[32 + g * 8 + 4];
        *(float4*)&b1r[0]  = *(const float4*)&b1[g * 8];
        *(float4*)&b1r[4]  = *(const float4*)&b1[g * 8 + 4];
        *(float4*)&b1r[8]  = *(const float4*)&b1[32 + g * 8];
        *(float4*)&b1r[12] = *(const float4*)&b1[32 + g * 8 + 4];
    }
    const float px = pos[(size_t)(b * 1024 + nq0 + lq) * 3 + 0];
    const float py = pos[(size_t)(b * 1024 + nq0 + lq) * 3 + 1];
    const float pz = pos[(size_t)(b * 1024 + nq0 + lq) * 3 + 2];

    bh8 w2fa, w2fb;                     // w2 B-frags (pre-scaled by log2e)
#pragma unroll
    for (int e = 0; e < 8; ++e) {
        const int k0e = g * 8 + e, k1e = 32 + g * 8 + e;
        w2fa[e] = (short)((lq < 8) ? f2bf(w2[k0e * 8 + lq] * LOG2E) : 0);
        w2fb[e] = (short)((lq < 8) ? f2bf(w2[k1e * 8 + lq] * LOG2E) : 0);
    }
    const float b2r = (lq < 8) ? b2[lq] * LOG2E : 0.f;

    bh8 qf0, qf1;                       // Q B-frags (pre-scaled 0.125*log2e)
    {
        const ushort* qp = qb + ((size_t)(b * 8 + w) * 1024 + nq0 + lq) * 64;
        qf0 = *(const bh8*)&qp[g * 8];
        qf1 = *(const bh8*)&qp[32 + g * 8];
    }

    f32x4 o[4];
#pragma unroll
    for (int dt = 0; dt < 4; ++dt) o[dt] = (f32x4){0.f, 0.f, 0.f, 0.f};
    float m_run = -INFINITY, l_run = 0.f;

#define STAGE(m0v) do { \
        const float4* _src = (const float4*)(apos + (size_t)(b * 1024 + (m0v)) * 64); \
        float4* _dst = (float4*)&a_m_s[0][0]; \
        _dst[tid] = _src[tid]; \
        _dst[tid + 512] = _src[tid + 512]; \
        if (tid < 192) pos_k_s[tid / 3][tid % 3] = \
            pos[(size_t)(b * 1024 + (m0v) + tid / 3) * 3 + tid % 3]; \
    } while (0)

    STAGE(k0);
    __syncthreads();

    for (int t16 = 0; t16 < nt; ++t16) {
        const int m0 = k0 + t16 * 64;

        // ---- bias MLP: wave w computes keys w*8..w*8+7, ALL heads, via MFMA ----
#pragma unroll
        for (int kk = 0; kk < 8; ++kk) {
            const int jl = w * 8 + kk;
            const float kx = pos_k_s[jl][0];
            const float ky = pos_k_s[jl][1];
            const float kz = pos_k_s[jl][2];
            const float dx = px - kx, dy = py - ky, dz = pz - kz;
            const float inv =
                1.f / (sqrtf(fmaf(dx, dx, fmaf(dy, dy, dz * dz))) + 1e-6f);
            const float* am = &a_m_s[jl][0];   // broadcast reads
            bh8 hf0, hf1;
#pragma unroll
            for (int e = 0; e < 8; ++e) {
                const float h0 =
                    fmaxf(fmaf(a_n[e] - am[g * 8 + e], inv, b1r[e]), 0.f);
                const float h1 =
                    fmaxf(fmaf(a_n[8 + e] - am[32 + g * 8 + e], inv, b1r[8 + e]), 0.f);
                hf0[e] = (short)f2bf(h0);
                hf1[e] = (short)f2bf(h1);
            }
            f32x4 acc = (f32x4){0.f, 0.f, 0.f, 0.f};
            acc = __builtin_amdgcn_mfma_f32_16x16x32_bf16(hf0, w2fa, acc, 0, 0, 0);
            acc = __builtin_amdgcn_mfma_f32_16x16x32_bf16(hf1, w2fb, acc, 0, 0, 0);
            if (lq < 8) {   // D: col=lq=head, row=g*4+r=query; store f16
#pragma unroll
                for (int r = 0; r < 4; ++r)
                    bias_s[lq * 1100 + (g * 4 + r) * 68 + jl] = f2h(acc[r] + b2r);
            }
        }
        __syncthreads();   // bias_s visible cross-wave; a_m reads done

        if (t16 < nt - 1) STAGE(m0 + 64);   // prefetch (consumed after barrier)

        // ---- S^T = mfma(K_tile, Q^T): D col=lq=query, row=g*4+r=key-local ----
        const ushort* kbp = kb + ((size_t)(b * 8 + w) * 1024 + m0) * 64;
        f32x4 s[4];
#pragma unroll
        for (int at = 0; at < 4; ++at) {
            const bh8 kf0 = *(const bh8*)&kbp[(at * 16 + lq) * 64 + g * 8];
            const bh8 kf1 = *(const bh8*)&kbp[(at * 16 + lq) * 64 + 32 + g * 8];
            f32x4 z = (f32x4){0.f, 0.f, 0.f, 0.f};
            z = __builtin_amdgcn_mfma_f32_16x16x32_bf16(kf0, qf0, z, 0, 0, 0);
            s[at] = __builtin_amdgcn_mfma_f32_16x16x32_bf16(kf1, qf1, z, 0, 0, 0);
        }

        // ---- online softmax in log2 domain (reduce over lanes ^16,^32) ----
        float sv[16];
        float pmax = -INFINITY;
#pragma unroll
        for (int at = 0; at < 4; ++at) {
            const int bb = w * 1100 + lq * 68 + at * 16 + g * 4;
            const uint2 bu = *(const uint2*)&bias_s[bb];
            sv[at * 4 + 0] = s[at][0] + h2f((ushort)(bu.x & 0xffff));
            sv[at * 4 + 1] = s[at][1] + h2f((ushort)(bu.x >> 16));
            sv[at * 4 + 2] = s[at][2] + h2f((ushort)(bu.y & 0xffff));
            sv[at * 4 + 3] = s[at][3] + h2f((ushort)(bu.y >> 16));
#pragma unroll
            for (int r = 0; r < 4; ++r) pmax = fmaxf(pmax, sv[at * 4 + r]);
        }
        pmax = fmaxf(pmax, __shfl_xor(pmax, 16));
        pmax = fmaxf(pmax, __shfl_xor(pmax, 32));
        const float mnew = fmaxf(m_run, pmax);
        const float alpha = exp2f(m_run - mnew);
        m_run = mnew;

        float rs = 0.f;
        ushort pb[16];
#pragma unroll
        for (int i = 0; i < 16; ++i) {
            const float p = exp2f(sv[i] - mnew);
            pb[i] = f2bf(p);
            rs += p;
        }
        rs += __shfl_xor(rs, 16);
        rs += __shfl_xor(rs, 32);
        l_run = l_run * alpha + rs;

#pragma unroll
        for (int at = 0; at < 4; ++at) {   // P -> wave-private LDS (no barrier)
            uint2 uv;
            uv.x = (unsigned)pb[at * 4 + 0] | ((unsigned)pb[at * 4 + 1] << 16);
            uv.y = (unsigned)pb[at * 4 + 2] | ((unsigned)pb[at * 4 + 3] << 16);
            *(uint2*)&p_lds[w][lq][at * 16 + g * 4] = uv;
        }
        red_s[w][lq] = alpha;

        float ar[4];
#pragma unroll
        for (int r = 0; r < 4; ++r) ar[r] = red_s[w][g * 4 + r];
#pragma unroll
        for (int dt = 0; dt < 4; ++dt) {
            o[dt][0] *= ar[0]; o[dt][1] *= ar[1];
            o[dt][2] *= ar[2]; o[dt][3] *= ar[3];
        }

        // ---- PV = mfma(P, V^T-frags): D col=lq=d-local, row=g*4+r=query ----
        const bh8 pa0 = *(const bh8*)&p_lds[w][lq][g * 8];
        const bh8 pa1 = *(const bh8*)&p_lds[w][lq][32 + g * 8];
        const ushort* vtp = vTb + ((size_t)(b * 8 + w) * 64) * 1024 + m0;
#pragma unroll
        for (int dt = 0; dt < 4; ++dt) {
            const bh8 vf0 = *(const bh8*)&vtp[(dt * 16 + lq) * 1024 + g * 8];
            const bh8 vf1 = *(const bh8*)&vtp[(dt * 16 + lq) * 1024 + 32 + g * 8];
            o[dt] = __builtin_amdgcn_mfma_f32_16x16x32_bf16(pa0, vf0, o[dt], 0, 0, 0);
            o[dt] = __builtin_amdgcn_mfma_f32_16x16x32_bf16(pa1, vf1, o[dt], 0, 0, 0);
        }
        __syncthreads();   // bias_s reads + a_m writes done before next tile
    }

    // ---- epilogue: unnormalized o + (m,l) per query (m in log2 domain) ----
    if (g == 0) {
        float2 mlv;
        mlv.x = m_run;
        mlv.y = l_run;
        *(float2*)&mlp[((size_t)(b * 8 + w) * 1024 + nq0 + lq) * 2] = mlv;
    }
#pragma unroll
    for (int dt = 0; dt < 4; ++dt)
#pragma unroll
        for (int r = 0; r < 4; ++r)
            outp[(size_t)(b * 1024 + nq0 + g * 4 + r) * 512 + w * 64 + dt * 16 + lq] =
                o[dt][r];
#undef STAGE
}

// ---------------- kernel 3: combine key parts (log2-domain m) ---------------
// Part-0 o lives in outF (f32) and is rewritten in place (same indices).
__global__ __launch_bounds__(256) void combine_parts(
    const float* __restrict__ o1, const float* __restrict__ o2,
    const float* __restrict__ ml0, const float* __restrict__ ml1,
    const float* __restrict__ ml2,
    float* __restrict__ outF, int nparts)
{
    const int idx = blockIdx.x * 256 + threadIdx.x;   // < 524288
    const size_t c4 = (size_t)idx * 4;
    const int row = idx >> 7;            // b*1024+n
    const int coff = (idx & 127) * 4;
    const int h = coff >> 6;
    const int b = row >> 10, n = row & 1023;
    const size_t mli = ((size_t)(b * 8 + h) * 1024 + n) * 2;
    const float2 v0 = *(const float2*)&ml0[mli];
    const float2 v1 = *(const float2*)&ml1[mli];
    float2 v2 = make_float2(-INFINITY, 0.f);
    if (nparts == 3) v2 = *(const float2*)&ml2[mli];
    const float m = fmaxf(fmaxf(v0.x, v1.x), v2.x);
    const float e0 = exp2f(v0.x - m), e1 = exp2f(v1.x - m);
    const float e2 = (nparts == 3) ? exp2f(v2.x - m) : 0.f;
    const float inv = 1.f / (v0.y * e0 + v1.y * e1 + v2.y * e2);
    const float4 a = *(const float4*)&outF[c4];
    const float4 bb = *(const float4*)&o1[c4];
    float4 cc = make_float4(0.f, 0.f, 0.f, 0.f);
    if (nparts == 3) cc = *(const float4*)&o2[c4];
    float4 r;
    r.x = (a.x * e0 + bb.x * e1 + cc.x * e2) * inv;
    r.y = (a.y * e0 + bb.y * e1 + cc.y * e2) * inv;
    r.z = (a.z * e0 + bb.z * e1 + cc.z * e2) * inv;
    r.w = (a.w * e0 + bb.w * e1 + cc.w * e2) * inv;
    *(float4*)&outF[c4] = r;
}

extern "C" void kernel_launch(void* const* d_in, const int* in_sizes, int n_in,
                              void* d_out, int out_size, void* d_ws, size_t ws_size,
                              hipStream_t stream) {
    const float* x    = (const float*)d_in[0];
    const float* pos  = (const float*)d_in[1];
    const float* wqkv = (const float*)d_in[2];
    const float* bqkv = (const float*)d_in[3];
    const float* w1   = (const float*)d_in[4];
    const float* b1   = (const float*)d_in[5];
    const float* w2   = (const float*)d_in[6];
    const float* b2   = (const float*)d_in[7];
    float* out = (float*)d_out;

    char* W = (char*)d_ws;
    ushort* qb   = (ushort*)W;
    ushort* kb   = (ushort*)(W + 4194304);
    ushort* vTb  = (ushort*)(W + 8388608);
    float*  apos = (float*)(W + 12582912);
    ushort* xb   = (ushort*)(W + 13631488);

    const size_t NEED3 = 31195136;
    const int nparts = (ws_size >= NEED3) ? 3 : 2;

    ushort *wTh, *wTl;
    float *outp1, *outp2, *ml0, *ml1, *ml2;
    if (nparts == 3) {
        wTh   = (ushort*)(W + 17825792);
        wTl   = (ushort*)(W + 19398656);
        outp1 = (float*)(W + 13631488);   // overlays xb/wTh/wTl (dead post-qkv)
        outp2 = (float*)(W + 22020096);
        ml0   = (float*)(W + 30408704);
        ml1   = (float*)(W + 30670848);
        ml2   = (float*)(W + 30932992);
    } else {
        wTh   = (ushort*)(W + 22020096);
        wTl   = (ushort*)(W + 23592960);
        outp1 = (float*)(W + 13631488);   // overlays xb (dead post-qkv)
        outp2 = outp1;                    // unused
        ml0   = (float*)(W + 22020096);   // overlays wTh (dead post-qkv)
        ml1   = (float*)(W + 22282240);
        ml2   = ml0;                      // unused
    }
    float* outp0 = out;                   // d_out holds part-0 f32

    hipLaunchKernelGGL(prep_kernel, dim3(3264), dim3(256), 0, stream,
                       x, pos, w1, wqkv, xb, wTh, wTl, apos);
    hipLaunchKernelGGL(qkv_mfma, dim3(32, 24), dim3(256), 0, stream,
                       xb, wTh, wTl, bqkv, qb, kb, vTb);
    hipLaunchKernelGGL(attn_fused, dim3(256 * nparts), dim3(512), 0, stream,
                       qb, kb, vTb, apos, pos, b1, w2, b2,
                       outp0, outp1, outp2, ml0, ml1, ml2, nparts);
    hipLaunchKernelGGL(combine_parts, dim3(2048), dim3(256), 0, stream,
                       outp1, outp2, ml0, ml1, ml2, out, nparts);
}